// Round 1
// baseline (4010.941 us; speedup 1.0000x reference)
//
#include <hip/hip_runtime.h>

#define NN 200000
#define NE 400000
#define HD 128
#define NL 3
#define NG 4096
#define BN_EPS 1e-5f

// ---------------- workspace layout (bytes) ----------------
#define OFF_DINV  0UL                  // NN floats        (800,000 B)
#define OFF_H     800000UL             // NN*HD floats     (102,400,000 B)
#define OFF_U     103200000UL          // NN*HD floats
#define OFF_ACC   205600000UL          // NN*HD floats
#define OFF_POOL  308000000UL          // NG*HD floats     (2,097,152 B)
#define OFF_CNT   310097152UL          // NG floats        (16,384 B)
#define OFF_CSUM  310113536UL          // NL*HD floats     (1,536 B)
#define OFF_CSQ   310115072UL          // NL*HD floats     (1,536 B)
#define OFF_SCALE 310116608UL          // HD floats
#define OFF_SHIFT 310117120UL          // HD floats

__global__ void set_deg_one(float* deg) {
    int i = blockIdx.x * blockDim.x + threadIdx.x;
    if (i < NN) deg[i] = 1.0f;
}

__global__ void count_deg(const int* __restrict__ col, float* __restrict__ deg) {
    int e = blockIdx.x * blockDim.x + threadIdx.x;
    if (e < NE) atomicAdd(&deg[col[e]], 1.0f);
}

__global__ void finalize_dinv(float* deg) {
    int i = blockIdx.x * blockDim.x + threadIdx.x;
    if (i < NN) deg[i] = rsqrtf(deg[i]);
}

// O[r][c] = sum_k A[r][k] * W[k][c]  (+bias)  (*dinv[r])  ; optionally copy to O2.
// Block: 256 threads = 16 rows x 16 col-groups (8 cols each). W staged in LDS (64 KB).
template <bool ADD_BIAS, bool SCALE_DINV, bool COPY2>
__launch_bounds__(256)
__global__ void gemm128(const float* __restrict__ A, const float* __restrict__ W,
                        const float* __restrict__ bias, const float* __restrict__ dinv,
                        float* __restrict__ O, float* __restrict__ O2, int M) {
    __shared__ float Wl[HD * HD];
    float4* Wl4 = (float4*)Wl;
    const float4* W4 = (const float4*)W;
    for (int i = threadIdx.x; i < HD * HD / 4; i += 256) Wl4[i] = W4[i];
    __syncthreads();

    int r = blockIdx.x * 16 + (threadIdx.x >> 4);
    int cg = threadIdx.x & 15;       // col group: cols [cg*8, cg*8+8)
    if (r >= M) return;

    const float4* A4 = (const float4*)(A + (size_t)r * HD);
    float4 acc0 = {0.f, 0.f, 0.f, 0.f};
    float4 acc1 = {0.f, 0.f, 0.f, 0.f};
    for (int k4 = 0; k4 < 32; ++k4) {
        float4 a = A4[k4];
        float av[4] = {a.x, a.y, a.z, a.w};
#pragma unroll
        for (int j = 0; j < 4; ++j) {
            float4 w0 = Wl4[(k4 * 4 + j) * 32 + cg * 2];
            float4 w1 = Wl4[(k4 * 4 + j) * 32 + cg * 2 + 1];
            acc0.x = fmaf(av[j], w0.x, acc0.x);
            acc0.y = fmaf(av[j], w0.y, acc0.y);
            acc0.z = fmaf(av[j], w0.z, acc0.z);
            acc0.w = fmaf(av[j], w0.w, acc0.w);
            acc1.x = fmaf(av[j], w1.x, acc1.x);
            acc1.y = fmaf(av[j], w1.y, acc1.y);
            acc1.z = fmaf(av[j], w1.z, acc1.z);
            acc1.w = fmaf(av[j], w1.w, acc1.w);
        }
    }
    if (ADD_BIAS) {
        float4 b0 = ((const float4*)bias)[cg * 2];
        float4 b1 = ((const float4*)bias)[cg * 2 + 1];
        acc0.x += b0.x; acc0.y += b0.y; acc0.z += b0.z; acc0.w += b0.w;
        acc1.x += b1.x; acc1.y += b1.y; acc1.z += b1.z; acc1.w += b1.w;
    }
    if (SCALE_DINV) {
        float s = dinv[r];
        acc0.x *= s; acc0.y *= s; acc0.z *= s; acc0.w *= s;
        acc1.x *= s; acc1.y *= s; acc1.z *= s; acc1.w *= s;
    }
    float4* Op = (float4*)(O + (size_t)r * HD + cg * 8);
    Op[0] = acc0; Op[1] = acc1;
    if (COPY2) {
        float4* O2p = (float4*)(O2 + (size_t)r * HD + cg * 8);
        O2p[0] = acc0; O2p[1] = acc1;
    }
}

// acc[col[e]][:] += u[row[e]][:]   (32 threads per edge, float4 each)
__global__ void edge_scatter(const int* __restrict__ row, const int* __restrict__ col,
                             const float* __restrict__ u, float* __restrict__ acc) {
    int idx = blockIdx.x * blockDim.x + threadIdx.x;
    int e = idx >> 5;
    int q = idx & 31;
    if (e >= NE) return;
    int rs = row[e];
    int cd = col[e];
    float4 v = *(const float4*)(u + (size_t)rs * HD + q * 4);
    float* dst = acc + (size_t)cd * HD + q * 4;
    atomicAdd(dst + 0, v.x);
    atomicAdd(dst + 1, v.y);
    atomicAdd(dst + 2, v.z);
    atomicAdd(dst + 3, v.w);
}

#define BN_ROWS 512
__global__ void bn_stats(const float* __restrict__ acc, const float* __restrict__ dinv,
                         float* __restrict__ colsum, float* __restrict__ colsumsq) {
    int c = threadIdx.x & 127;
    int rg = threadIdx.x >> 7;   // 0..1
    int r0 = blockIdx.x * BN_ROWS;
    int r1 = min(r0 + BN_ROWS, NN);
    float s1 = 0.f, s2 = 0.f;
    for (int r = r0 + rg; r < r1; r += 2) {
        float y = dinv[r] * acc[(size_t)r * HD + c];
        s1 += y;
        s2 += y * y;
    }
    __shared__ float sh1[2][HD];
    __shared__ float sh2[2][HD];
    sh1[rg][c] = s1;
    sh2[rg][c] = s2;
    __syncthreads();
    if (threadIdx.x < HD) {
        atomicAdd(&colsum[c], sh1[0][c] + sh1[1][c]);
        atomicAdd(&colsumsq[c], sh2[0][c] + sh2[1][c]);
    }
}

__global__ void bn_finalize(const float* __restrict__ colsum, const float* __restrict__ colsumsq,
                            const float* __restrict__ gamma, const float* __restrict__ beta,
                            float* __restrict__ scale, float* __restrict__ shift) {
    int c = threadIdx.x;
    float invn = 1.0f / (float)NN;
    float m = colsum[c] * invn;
    float v = colsumsq[c] * invn - m * m;
    float sc = gamma[c] * rsqrtf(v + BN_EPS);
    scale[c] = sc;
    shift[c] = beta[c] - m * sc;
}

// h += relu(dinv[r]*acc[r][c]*scale[c] + shift[c])
__global__ void bn_apply(const float* __restrict__ acc, const float* __restrict__ dinv,
                         const float* __restrict__ scale, const float* __restrict__ shift,
                         float* __restrict__ h) {
    int idx = blockIdx.x * blockDim.x + threadIdx.x;
    int r = idx >> 5;
    int q = idx & 31;
    if (r >= NN) return;
    float d = dinv[r];
    float4 a = *(const float4*)(acc + (size_t)r * HD + q * 4);
    float4 sc = *(const float4*)(scale + q * 4);
    float4 sf = *(const float4*)(shift + q * 4);
    float4* hp = (float4*)(h + (size_t)r * HD + q * 4);
    float4 hv = *hp;
    hv.x += fmaxf(fmaf(d * a.x, sc.x, sf.x), 0.f);
    hv.y += fmaxf(fmaf(d * a.y, sc.y, sf.y), 0.f);
    hv.z += fmaxf(fmaf(d * a.z, sc.z, sf.z), 0.f);
    hv.w += fmaxf(fmaf(d * a.w, sc.w, sf.w), 0.f);
    *hp = hv;
}

__global__ void pool_kernel(const float* __restrict__ h, const int* __restrict__ batch,
                            float* __restrict__ pool, float* __restrict__ cnt) {
    int idx = blockIdx.x * blockDim.x + threadIdx.x;
    int r = idx >> 5;
    int q = idx & 31;
    if (r >= NN) return;
    int g = batch[r];
    float4 v = *(const float4*)(h + (size_t)r * HD + q * 4);
    float* dst = pool + (size_t)g * HD + q * 4;
    atomicAdd(dst + 0, v.x);
    atomicAdd(dst + 1, v.y);
    atomicAdd(dst + 2, v.z);
    atomicAdd(dst + 3, v.w);
    if (q == 0) atomicAdd(&cnt[g], 1.0f);
}

__launch_bounds__(128)
__global__ void out_gemm(const float* __restrict__ pool, const float* __restrict__ cnt,
                         const float* __restrict__ Wout, const float* __restrict__ bout,
                         float* __restrict__ out) {
    __shared__ float hb[HD];
    int g = blockIdx.x;
    int c = threadIdx.x;
    float ic = 1.0f / fmaxf(cnt[g], 1.0f);
    hb[c] = pool[(size_t)g * HD + c] * ic;
    __syncthreads();
    float o = bout[c];
#pragma unroll 8
    for (int k = 0; k < HD; ++k) o = fmaf(hb[k], Wout[k * HD + c], o);
    out[(size_t)g * HD + c] = o;
}

extern "C" void kernel_launch(void* const* d_in, const int* in_sizes, int n_in,
                              void* d_out, int out_size, void* d_ws, size_t ws_size,
                              hipStream_t stream) {
    const float* x      = (const float*)d_in[0];
    const float* W_in   = (const float*)d_in[1];
    const float* b_in   = (const float*)d_in[2];
    const float* W_conv = (const float*)d_in[3];
    // d_in[4] = b_conv — cancels exactly inside BatchNorm (shifts mean only), unused.
    const float* gamma  = (const float*)d_in[5];
    const float* beta   = (const float*)d_in[6];
    const float* W_out  = (const float*)d_in[7];
    const float* b_out  = (const float*)d_in[8];
    const int*   edge   = (const int*)d_in[9];
    const int*   batch  = (const int*)d_in[10];
    float* out = (float*)d_out;

    char* ws = (char*)d_ws;
    float* dinv  = (float*)(ws + OFF_DINV);
    float* h     = (float*)(ws + OFF_H);
    float* u     = (float*)(ws + OFF_U);
    float* acc   = (float*)(ws + OFF_ACC);
    float* pool  = (float*)(ws + OFF_POOL);
    float* cnt   = (float*)(ws + OFF_CNT);
    float* csum  = (float*)(ws + OFF_CSUM);
    float* csq   = (float*)(ws + OFF_CSQ);
    float* scale = (float*)(ws + OFF_SCALE);
    float* shift = (float*)(ws + OFF_SHIFT);

    const int* row = edge;        // sources
    const int* col = edge + NE;   // targets

    // zero pool/cnt/stats in one contiguous memset (they are laid out adjacently)
    hipMemsetAsync(ws + OFF_POOL, 0, (OFF_CSQ + NL * HD * 4) - OFF_POOL, stream);

    set_deg_one<<<(NN + 255) / 256, 256, 0, stream>>>(dinv);
    count_deg<<<(NE + 255) / 256, 256, 0, stream>>>(col, dinv);
    finalize_dinv<<<(NN + 255) / 256, 256, 0, stream>>>(dinv);

    // h = x @ W_in + b_in
    gemm128<true, false, false><<<(NN + 15) / 16, 256, 0, stream>>>(
        x, W_in, b_in, nullptr, h, nullptr, NN);

    for (int l = 0; l < NL; ++l) {
        // u = (h @ W_conv[l]) * dinv ; acc = u (self-loop term pre-seeded)
        gemm128<false, true, true><<<(NN + 15) / 16, 256, 0, stream>>>(
            h, W_conv + (size_t)l * HD * HD, nullptr, dinv, u, acc, NN);
        edge_scatter<<<(NE * 32 + 255) / 256, 256, 0, stream>>>(row, col, u, acc);
        bn_stats<<<(NN + BN_ROWS - 1) / BN_ROWS, 256, 0, stream>>>(
            acc, dinv, csum + l * HD, csq + l * HD);
        bn_finalize<<<1, HD, 0, stream>>>(
            csum + l * HD, csq + l * HD, gamma + l * HD, beta + l * HD, scale, shift);
        bn_apply<<<((size_t)NN * 32 + 255) / 256, 256, 0, stream>>>(
            acc, dinv, scale, shift, h);
    }

    pool_kernel<<<((size_t)NN * 32 + 255) / 256, 256, 0, stream>>>(h, batch, pool, cnt);
    out_gemm<<<NG, HD, 0, stream>>>(pool, cnt, W_out, b_out, out);
}

// Round 2
// 1460.990 us; speedup vs baseline: 2.7454x; 2.7454x over previous
//
#include <hip/hip_runtime.h>

#define NN 200000
#define NE 400000
#define HD 128
#define NL 3
#define NG 4096
#define BN_EPS 1e-5f

// ---------------- workspace layout (bytes) ----------------
#define OFF_DINV  0UL                  // NN floats
#define OFF_H     800000UL             // NN*HD floats
#define OFF_U     103200000UL          // NN*HD floats
#define OFF_ACC   205600000UL          // NN*HD floats (holds y = dinv*agg)
#define OFF_POOL  308000000UL          // NG*HD floats
#define OFF_CNT   310097152UL          // NG floats
#define OFF_CSUM  310113536UL          // NL*HD floats
#define OFF_CSQ   310115072UL          // NL*HD floats
#define OFF_SCALE 310116608UL          // HD floats
#define OFF_SHIFT 310117120UL          // HD floats
#define OFF_CNTI  310117632UL          // NN ints (in-degree, excl self)
#define OFF_OFFS  310917632UL          // (NN+1) ints + pad
#define OFF_CUR   311717648UL          // NN ints (fill cursors)
#define OFF_SRCS  312517648UL          // NE ints (CSR sources)
#define OFF_BSUM  314117648UL          // scan partials (256 ints)

#define SCAN_B 196                     // ceil(NN/1024)

__global__ void count_deg_i(const int* __restrict__ col, int* __restrict__ cnt) {
    int e = blockIdx.x * blockDim.x + threadIdx.x;
    if (e < NE) atomicAdd(&cnt[col[e]], 1);
}

__global__ void finalize_dinv(const int* __restrict__ cnt, float* __restrict__ dinv) {
    int i = blockIdx.x * blockDim.x + threadIdx.x;
    if (i < NN) dinv[i] = rsqrtf((float)(cnt[i] + 1));   // +1 self-loop
}

// ---- exclusive scan of cnt[NN] -> offs[NN+1] (three phases) ----
__global__ void scan_phase1(const int* __restrict__ cnt, int* __restrict__ bsum) {
    __shared__ int sh[256];
    int b = blockIdx.x, t = threadIdx.x;
    int base = b * 1024 + t * 4;
    int s = 0;
#pragma unroll
    for (int j = 0; j < 4; ++j) if (base + j < NN) s += cnt[base + j];
    sh[t] = s;
    __syncthreads();
    for (int st = 128; st > 0; st >>= 1) {
        if (t < st) sh[t] += sh[t + st];
        __syncthreads();
    }
    if (t == 0) bsum[b] = sh[0];
}

__global__ void scan_phase2(int* __restrict__ bsum, int* __restrict__ offs) {
    if (threadIdx.x == 0) {
        int run = 0;
        for (int i = 0; i < SCAN_B; ++i) { int v = bsum[i]; bsum[i] = run; run += v; }
        offs[NN] = NE;
    }
}

__global__ void scan_phase3(const int* __restrict__ cnt, const int* __restrict__ bsum,
                            int* __restrict__ offs) {
    __shared__ int sh[256];
    int b = blockIdx.x, t = threadIdx.x;
    int base = b * 1024 + t * 4;
    int v[4];
    int s = 0;
#pragma unroll
    for (int j = 0; j < 4; ++j) { v[j] = (base + j < NN) ? cnt[base + j] : 0; s += v[j]; }
    sh[t] = s;
    __syncthreads();
    for (int st = 1; st < 256; st <<= 1) {
        int x = (t >= st) ? sh[t - st] : 0;
        __syncthreads();
        sh[t] += x;
        __syncthreads();
    }
    int run = sh[t] - s + bsum[b];   // exclusive prefix for this thread's range
#pragma unroll
    for (int j = 0; j < 4; ++j) {
        if (base + j < NN) { offs[base + j] = run; run += v[j]; }
    }
}

__global__ void fill_csr(const int* __restrict__ row, const int* __restrict__ col,
                         const int* __restrict__ offs, int* __restrict__ cur,
                         int* __restrict__ srcs) {
    int e = blockIdx.x * blockDim.x + threadIdx.x;
    if (e >= NE) return;
    int c = col[e];
    int p = offs[c] + atomicAdd(&cur[c], 1);
    srcs[p] = row[e];
}

// O[r][:] = A[r][:] @ W (+bias) (*dinv[r]).
// 512 threads = 32 rowgroups(4 rows) x 16 colgroups. cols {4cg..4cg+3, 64+4cg..}
// -> LDS float4 index cg covers 32 banks across 8 lanes (2-way alias = free).
template <bool ADD_BIAS, bool SCALE_DINV>
__launch_bounds__(512)
__global__ void gemm128(const float* __restrict__ A, const float* __restrict__ W,
                        const float* __restrict__ bias, const float* __restrict__ dinv,
                        float* __restrict__ O, int M) {
    __shared__ float Wl[HD * HD];
    float4* Wl4 = (float4*)Wl;
    const float4* W4 = (const float4*)W;
    for (int i = threadIdx.x; i < HD * HD / 4; i += 512) Wl4[i] = W4[i];
    __syncthreads();

    int rg = threadIdx.x >> 4;        // 0..31
    int cg = threadIdx.x & 15;        // 0..15
    int r0 = blockIdx.x * 128 + rg * 4;
    if (r0 >= M) return;              // M % 4 == 0, whole 4-row slice valid or not

    const float4* A4 = (const float4*)(A + (size_t)r0 * HD);
    float4 acc0[4], acc1[4];
#pragma unroll
    for (int i = 0; i < 4; ++i) {
        acc0[i] = make_float4(0.f, 0.f, 0.f, 0.f);
        acc1[i] = make_float4(0.f, 0.f, 0.f, 0.f);
    }

    for (int k4 = 0; k4 < 32; ++k4) {
        float4 a[4];
#pragma unroll
        for (int i = 0; i < 4; ++i) a[i] = A4[i * 32 + k4];
#pragma unroll
        for (int j = 0; j < 4; ++j) {
            float4 w0 = Wl4[(k4 * 4 + j) * 32 + cg];
            float4 w1 = Wl4[(k4 * 4 + j) * 32 + 16 + cg];
#pragma unroll
            for (int i = 0; i < 4; ++i) {
                float av = (j == 0) ? a[i].x : (j == 1) ? a[i].y : (j == 2) ? a[i].z : a[i].w;
                acc0[i].x = fmaf(av, w0.x, acc0[i].x);
                acc0[i].y = fmaf(av, w0.y, acc0[i].y);
                acc0[i].z = fmaf(av, w0.z, acc0[i].z);
                acc0[i].w = fmaf(av, w0.w, acc0[i].w);
                acc1[i].x = fmaf(av, w1.x, acc1[i].x);
                acc1[i].y = fmaf(av, w1.y, acc1[i].y);
                acc1[i].z = fmaf(av, w1.z, acc1[i].z);
                acc1[i].w = fmaf(av, w1.w, acc1[i].w);
            }
        }
    }

    float4 b0 = make_float4(0.f, 0.f, 0.f, 0.f), b1 = b0;
    if (ADD_BIAS) {
        b0 = ((const float4*)bias)[cg];
        b1 = ((const float4*)bias)[16 + cg];
    }
#pragma unroll
    for (int i = 0; i < 4; ++i) {
        int r = r0 + i;
        float s = SCALE_DINV ? dinv[r] : 1.0f;
        float4 o0 = acc0[i], o1 = acc1[i];
        if (ADD_BIAS) {
            o0.x += b0.x; o0.y += b0.y; o0.z += b0.z; o0.w += b0.w;
            o1.x += b1.x; o1.y += b1.y; o1.z += b1.z; o1.w += b1.w;
        }
        if (SCALE_DINV) {
            o0.x *= s; o0.y *= s; o0.z *= s; o0.w *= s;
            o1.x *= s; o1.y *= s; o1.z *= s; o1.w *= s;
        }
        float4* O4 = (float4*)(O + (size_t)r * HD);
        O4[cg] = o0;
        O4[16 + cg] = o1;
    }
}

// acc[i] = y_i = dinv[i]*(u[i] + sum_{e: col=i} u[src[e]]); fused BN col stats.
// grid-stride, 8 nodes/block-iter (32 lanes per node, float4/lane).
#define GATHER_BLOCKS 1024
__global__ void gather_bn(const int* __restrict__ offs, const int* __restrict__ srcs,
                          const float* __restrict__ u, const float* __restrict__ dinv,
                          float* __restrict__ acc,
                          float* __restrict__ colsum, float* __restrict__ colsumsq) {
    const float4* u4 = (const float4*)u;
    float4* acc4 = (float4*)acc;
    int n = threadIdx.x >> 5;     // node slot 0..7
    int q = threadIdx.x & 31;     // float4 lane within row
    float4 t1 = make_float4(0.f, 0.f, 0.f, 0.f);
    float4 t2 = make_float4(0.f, 0.f, 0.f, 0.f);

    for (int node = blockIdx.x * 8 + n; node < NN; node += GATHER_BLOCKS * 8) {
        float4 s = u4[(size_t)node * 32 + q];     // self-loop seed
        int k1 = offs[node + 1];
        for (int k = offs[node]; k < k1; ++k) {
            int src = srcs[k];
            float4 v = u4[(size_t)src * 32 + q];
            s.x += v.x; s.y += v.y; s.z += v.z; s.w += v.w;
        }
        float d = dinv[node];
        s.x *= d; s.y *= d; s.z *= d; s.w *= d;
        acc4[(size_t)node * 32 + q] = s;
        t1.x += s.x; t1.y += s.y; t1.z += s.z; t1.w += s.w;
        t2.x += s.x * s.x; t2.y += s.y * s.y; t2.z += s.z * s.z; t2.w += s.w * s.w;
    }

    __shared__ float sh1[8][HD];
    __shared__ float sh2[8][HD];
    *(float4*)&sh1[n][q * 4] = t1;
    *(float4*)&sh2[n][q * 4] = t2;
    __syncthreads();
    if (threadIdx.x < HD) {
        int c = threadIdx.x;
        float a1 = 0.f, a2 = 0.f;
#pragma unroll
        for (int i = 0; i < 8; ++i) { a1 += sh1[i][c]; a2 += sh2[i][c]; }
        atomicAdd(&colsum[c], a1);
        atomicAdd(&colsumsq[c], a2);
    }
}

__global__ void bn_finalize(const float* __restrict__ colsum, const float* __restrict__ colsumsq,
                            const float* __restrict__ gamma, const float* __restrict__ beta,
                            float* __restrict__ scale, float* __restrict__ shift) {
    int c = threadIdx.x;
    float invn = 1.0f / (float)NN;
    float m = colsum[c] * invn;
    float v = colsumsq[c] * invn - m * m;
    float sc = gamma[c] * rsqrtf(v + BN_EPS);
    scale[c] = sc;
    shift[c] = beta[c] - m * sc;
}

// h += relu(y*scale + shift);  y already includes dinv.
__global__ void bn_apply(const float* __restrict__ acc,
                         const float* __restrict__ scale, const float* __restrict__ shift,
                         float* __restrict__ h) {
    int idx = blockIdx.x * blockDim.x + threadIdx.x;
    int r = idx >> 5;
    int q = idx & 31;
    if (r >= NN) return;
    float4 a = *(const float4*)(acc + (size_t)r * HD + q * 4);
    float4 sc = *(const float4*)(scale + q * 4);
    float4 sf = *(const float4*)(shift + q * 4);
    float4* hp = (float4*)(h + (size_t)r * HD + q * 4);
    float4 hv = *hp;
    hv.x += fmaxf(fmaf(a.x, sc.x, sf.x), 0.f);
    hv.y += fmaxf(fmaf(a.y, sc.y, sf.y), 0.f);
    hv.z += fmaxf(fmaf(a.z, sc.z, sf.z), 0.f);
    hv.w += fmaxf(fmaf(a.w, sc.w, sf.w), 0.f);
    *hp = hv;
}

__global__ void pool_kernel(const float* __restrict__ h, const int* __restrict__ batch,
                            float* __restrict__ pool, float* __restrict__ cnt) {
    int idx = blockIdx.x * blockDim.x + threadIdx.x;
    int r = idx >> 5;
    int q = idx & 31;
    if (r >= NN) return;
    int g = batch[r];
    float4 v = *(const float4*)(h + (size_t)r * HD + q * 4);
    float* dst = pool + (size_t)g * HD + q * 4;
    atomicAdd(dst + 0, v.x);
    atomicAdd(dst + 1, v.y);
    atomicAdd(dst + 2, v.z);
    atomicAdd(dst + 3, v.w);
    if (q == 0) atomicAdd(&cnt[g], 1.0f);
}

__launch_bounds__(128)
__global__ void out_gemm(const float* __restrict__ pool, const float* __restrict__ cnt,
                         const float* __restrict__ Wout, const float* __restrict__ bout,
                         float* __restrict__ out) {
    __shared__ float hb[HD];
    int g = blockIdx.x;
    int c = threadIdx.x;
    float ic = 1.0f / fmaxf(cnt[g], 1.0f);
    hb[c] = pool[(size_t)g * HD + c] * ic;
    __syncthreads();
    float o = bout[c];
#pragma unroll 8
    for (int k = 0; k < HD; ++k) o = fmaf(hb[k], Wout[k * HD + c], o);
    out[(size_t)g * HD + c] = o;
}

extern "C" void kernel_launch(void* const* d_in, const int* in_sizes, int n_in,
                              void* d_out, int out_size, void* d_ws, size_t ws_size,
                              hipStream_t stream) {
    const float* x      = (const float*)d_in[0];
    const float* W_in   = (const float*)d_in[1];
    const float* b_in   = (const float*)d_in[2];
    const float* W_conv = (const float*)d_in[3];
    // d_in[4] = b_conv — cancels exactly inside BatchNorm (mean shift only), unused.
    const float* gamma  = (const float*)d_in[5];
    const float* beta   = (const float*)d_in[6];
    const float* W_out  = (const float*)d_in[7];
    const float* b_out  = (const float*)d_in[8];
    const int*   edge   = (const int*)d_in[9];
    const int*   batch  = (const int*)d_in[10];
    float* out = (float*)d_out;

    char* ws = (char*)d_ws;
    float* dinv  = (float*)(ws + OFF_DINV);
    float* h     = (float*)(ws + OFF_H);
    float* u     = (float*)(ws + OFF_U);
    float* acc   = (float*)(ws + OFF_ACC);
    float* pool  = (float*)(ws + OFF_POOL);
    float* cnt   = (float*)(ws + OFF_CNT);
    float* csum  = (float*)(ws + OFF_CSUM);
    float* csq   = (float*)(ws + OFF_CSQ);
    float* scale = (float*)(ws + OFF_SCALE);
    float* shift = (float*)(ws + OFF_SHIFT);
    int*   cnti  = (int*)(ws + OFF_CNTI);
    int*   offs  = (int*)(ws + OFF_OFFS);
    int*   cur   = (int*)(ws + OFF_CUR);
    int*   srcs  = (int*)(ws + OFF_SRCS);
    int*   bsum  = (int*)(ws + OFF_BSUM);

    const int* row = edge;        // sources
    const int* col = edge + NE;   // targets

    // zero: pool/cnt/stats region, and cnti/offs/cur region
    hipMemsetAsync(ws + OFF_POOL, 0, OFF_SHIFT + 512 - OFF_POOL, stream);
    hipMemsetAsync(ws + OFF_CNTI, 0, OFF_SRCS - OFF_CNTI, stream);

    // CSR build + dinv
    count_deg_i<<<(NE + 255) / 256, 256, 0, stream>>>(col, cnti);
    finalize_dinv<<<(NN + 255) / 256, 256, 0, stream>>>(cnti, dinv);
    scan_phase1<<<SCAN_B, 256, 0, stream>>>(cnti, bsum);
    scan_phase2<<<1, 64, 0, stream>>>(bsum, offs);
    scan_phase3<<<SCAN_B, 256, 0, stream>>>(cnti, bsum, offs);
    fill_csr<<<(NE + 255) / 256, 256, 0, stream>>>(row, col, offs, cur, srcs);

    // h = x @ W_in + b_in
    gemm128<true, false><<<(NN + 127) / 128, 512, 0, stream>>>(
        x, W_in, b_in, nullptr, h, NN);

    for (int l = 0; l < NL; ++l) {
        // u = (h @ W_conv[l]) * dinv
        gemm128<false, true><<<(NN + 127) / 128, 512, 0, stream>>>(
            h, W_conv + (size_t)l * HD * HD, nullptr, dinv, u, NN);
        gather_bn<<<GATHER_BLOCKS, 256, 0, stream>>>(
            offs, srcs, u, dinv, acc, csum + l * HD, csq + l * HD);
        bn_finalize<<<1, HD, 0, stream>>>(
            csum + l * HD, csq + l * HD, gamma + l * HD, beta + l * HD, scale, shift);
        bn_apply<<<((size_t)NN * 32 + 255) / 256, 256, 0, stream>>>(
            acc, scale, shift, h);
    }

    pool_kernel<<<((size_t)NN * 32 + 255) / 256, 256, 0, stream>>>(h, batch, pool, cnt);
    out_gemm<<<NG, HD, 0, stream>>>(pool, cnt, W_out, b_out, out);
}

// Round 3
// 1091.831 us; speedup vs baseline: 3.6736x; 1.3381x over previous
//
#include <hip/hip_runtime.h>

#define NN 200000
#define NE 400000
#define HD 128
#define NL 3
#define NG 4096
#define BN_EPS 1e-5f

// ---------------- workspace layout (bytes) ----------------
#define OFF_DINV  0UL                  // NN floats
#define OFF_H     800000UL             // NN*HD floats
#define OFF_U     103200000UL          // NN*HD floats
#define OFF_ACC   205600000UL          // NN*HD floats (holds y = dinv*agg)
#define OFF_POOL  308000000UL          // NG*HD floats (group means)
#define OFF_GSTART 310097152UL         // (NG+1) ints
#define OFF_CSUM  310113540UL          // NL*HD floats
#define OFF_CSQ   310115076UL          // NL*HD floats
#define OFF_SCALE 310116612UL          // HD floats
#define OFF_SHIFT 310117124UL          // HD floats
#define OFF_CNTI  310117636UL          // NN ints (in-degree, excl self)
#define OFF_OFFS  310917636UL          // (NN+1) ints + pad
#define OFF_CUR   311717652UL          // NN ints (fill cursors)
#define OFF_SRCS  312517652UL          // NE ints (CSR sources)
#define OFF_BSUM  314117652UL          // scan partials (256 ints)

#define SCAN_B 196                     // ceil(NN/1024)

__global__ void count_deg_i(const int* __restrict__ col, int* __restrict__ cnt) {
    int e = blockIdx.x * blockDim.x + threadIdx.x;
    if (e < NE) atomicAdd(&cnt[col[e]], 1);
}

__global__ void finalize_dinv(const int* __restrict__ cnt, float* __restrict__ dinv) {
    int i = blockIdx.x * blockDim.x + threadIdx.x;
    if (i < NN) dinv[i] = rsqrtf((float)(cnt[i] + 1));   // +1 self-loop
}

// ---- exclusive scan of cnt[NN] -> offs[NN+1] (three phases) ----
__global__ void scan_phase1(const int* __restrict__ cnt, int* __restrict__ bsum) {
    __shared__ int sh[256];
    int b = blockIdx.x, t = threadIdx.x;
    int base = b * 1024 + t * 4;
    int s = 0;
#pragma unroll
    for (int j = 0; j < 4; ++j) if (base + j < NN) s += cnt[base + j];
    sh[t] = s;
    __syncthreads();
    for (int st = 128; st > 0; st >>= 1) {
        if (t < st) sh[t] += sh[t + st];
        __syncthreads();
    }
    if (t == 0) bsum[b] = sh[0];
}

__global__ void scan_phase2(int* __restrict__ bsum, int* __restrict__ offs) {
    if (threadIdx.x == 0) {
        int run = 0;
        for (int i = 0; i < SCAN_B; ++i) { int v = bsum[i]; bsum[i] = run; run += v; }
        offs[NN] = NE;
    }
}

__global__ void scan_phase3(const int* __restrict__ cnt, const int* __restrict__ bsum,
                            int* __restrict__ offs) {
    __shared__ int sh[256];
    int b = blockIdx.x, t = threadIdx.x;
    int base = b * 1024 + t * 4;
    int v[4];
    int s = 0;
#pragma unroll
    for (int j = 0; j < 4; ++j) { v[j] = (base + j < NN) ? cnt[base + j] : 0; s += v[j]; }
    sh[t] = s;
    __syncthreads();
    for (int st = 1; st < 256; st <<= 1) {
        int x = (t >= st) ? sh[t - st] : 0;
        __syncthreads();
        sh[t] += x;
        __syncthreads();
    }
    int run = sh[t] - s + bsum[b];   // exclusive prefix for this thread's range
#pragma unroll
    for (int j = 0; j < 4; ++j) {
        if (base + j < NN) { offs[base + j] = run; run += v[j]; }
    }
}

__global__ void fill_csr(const int* __restrict__ row, const int* __restrict__ col,
                         const int* __restrict__ offs, int* __restrict__ cur,
                         int* __restrict__ srcs) {
    int e = blockIdx.x * blockDim.x + threadIdx.x;
    if (e >= NE) return;
    int c = col[e];
    int p = offs[c] + atomicAdd(&cur[c], 1);
    srcs[p] = row[e];
}

// O[r][:] = A[r][:] @ W (+bias) (*dinv[r]).
// 512 threads = 32 rowgroups(4 rows) x 16 colgroups. cols {4cg..4cg+3, 64+4cg..}
template <bool ADD_BIAS, bool SCALE_DINV>
__launch_bounds__(512)
__global__ void gemm128(const float* __restrict__ A, const float* __restrict__ W,
                        const float* __restrict__ bias, const float* __restrict__ dinv,
                        float* __restrict__ O, int M) {
    __shared__ float Wl[HD * HD];
    float4* Wl4 = (float4*)Wl;
    const float4* W4 = (const float4*)W;
    for (int i = threadIdx.x; i < HD * HD / 4; i += 512) Wl4[i] = W4[i];
    __syncthreads();

    int rg = threadIdx.x >> 4;        // 0..31
    int cg = threadIdx.x & 15;        // 0..15
    int r0 = blockIdx.x * 128 + rg * 4;
    if (r0 >= M) return;

    const float4* A4 = (const float4*)(A + (size_t)r0 * HD);
    float4 acc0[4], acc1[4];
#pragma unroll
    for (int i = 0; i < 4; ++i) {
        acc0[i] = make_float4(0.f, 0.f, 0.f, 0.f);
        acc1[i] = make_float4(0.f, 0.f, 0.f, 0.f);
    }

    for (int k4 = 0; k4 < 32; ++k4) {
        float4 a[4];
#pragma unroll
        for (int i = 0; i < 4; ++i) a[i] = A4[i * 32 + k4];
#pragma unroll
        for (int j = 0; j < 4; ++j) {
            float4 w0 = Wl4[(k4 * 4 + j) * 32 + cg];
            float4 w1 = Wl4[(k4 * 4 + j) * 32 + 16 + cg];
#pragma unroll
            for (int i = 0; i < 4; ++i) {
                float av = (j == 0) ? a[i].x : (j == 1) ? a[i].y : (j == 2) ? a[i].z : a[i].w;
                acc0[i].x = fmaf(av, w0.x, acc0[i].x);
                acc0[i].y = fmaf(av, w0.y, acc0[i].y);
                acc0[i].z = fmaf(av, w0.z, acc0[i].z);
                acc0[i].w = fmaf(av, w0.w, acc0[i].w);
                acc1[i].x = fmaf(av, w1.x, acc1[i].x);
                acc1[i].y = fmaf(av, w1.y, acc1[i].y);
                acc1[i].z = fmaf(av, w1.z, acc1[i].z);
                acc1[i].w = fmaf(av, w1.w, acc1[i].w);
            }
        }
    }

    float4 b0 = make_float4(0.f, 0.f, 0.f, 0.f), b1 = b0;
    if (ADD_BIAS) {
        b0 = ((const float4*)bias)[cg];
        b1 = ((const float4*)bias)[16 + cg];
    }
#pragma unroll
    for (int i = 0; i < 4; ++i) {
        int r = r0 + i;
        float s = SCALE_DINV ? dinv[r] : 1.0f;
        float4 o0 = acc0[i], o1 = acc1[i];
        if (ADD_BIAS) {
            o0.x += b0.x; o0.y += b0.y; o0.z += b0.z; o0.w += b0.w;
            o1.x += b1.x; o1.y += b1.y; o1.z += b1.z; o1.w += b1.w;
        }
        if (SCALE_DINV) {
            o0.x *= s; o0.y *= s; o0.z *= s; o0.w *= s;
            o1.x *= s; o1.y *= s; o1.z *= s; o1.w *= s;
        }
        float4* O4 = (float4*)(O + (size_t)r * HD);
        O4[cg] = o0;
        O4[16 + cg] = o1;
    }
}

// acc[i] = y_i = dinv[i]*(u[i] + sum_{e: col=i} u[src[e]]); fused BN col stats.
#define GATHER_BLOCKS 1024
__global__ void gather_bn(const int* __restrict__ offs, const int* __restrict__ srcs,
                          const float* __restrict__ u, const float* __restrict__ dinv,
                          float* __restrict__ acc,
                          float* __restrict__ colsum, float* __restrict__ colsumsq) {
    const float4* u4 = (const float4*)u;
    float4* acc4 = (float4*)acc;
    int n = threadIdx.x >> 5;     // node slot 0..7
    int q = threadIdx.x & 31;     // float4 lane within row
    float4 t1 = make_float4(0.f, 0.f, 0.f, 0.f);
    float4 t2 = make_float4(0.f, 0.f, 0.f, 0.f);

    for (int node = blockIdx.x * 8 + n; node < NN; node += GATHER_BLOCKS * 8) {
        float4 s = u4[(size_t)node * 32 + q];     // self-loop seed
        int k1 = offs[node + 1];
        for (int k = offs[node]; k < k1; ++k) {
            int src = srcs[k];
            float4 v = u4[(size_t)src * 32 + q];
            s.x += v.x; s.y += v.y; s.z += v.z; s.w += v.w;
        }
        float d = dinv[node];
        s.x *= d; s.y *= d; s.z *= d; s.w *= d;
        acc4[(size_t)node * 32 + q] = s;
        t1.x += s.x; t1.y += s.y; t1.z += s.z; t1.w += s.w;
        t2.x += s.x * s.x; t2.y += s.y * s.y; t2.z += s.z * s.z; t2.w += s.w * s.w;
    }

    __shared__ float sh1[8][HD];
    __shared__ float sh2[8][HD];
    *(float4*)&sh1[n][q * 4] = t1;
    *(float4*)&sh2[n][q * 4] = t2;
    __syncthreads();
    if (threadIdx.x < HD) {
        int c = threadIdx.x;
        float a1 = 0.f, a2 = 0.f;
#pragma unroll
        for (int i = 0; i < 8; ++i) { a1 += sh1[i][c]; a2 += sh2[i][c]; }
        atomicAdd(&colsum[c], a1);
        atomicAdd(&colsumsq[c], a2);
    }
}

__global__ void bn_finalize(const float* __restrict__ colsum, const float* __restrict__ colsumsq,
                            const float* __restrict__ gamma, const float* __restrict__ beta,
                            float* __restrict__ scale, float* __restrict__ shift) {
    int c = threadIdx.x;
    float invn = 1.0f / (float)NN;
    float m = colsum[c] * invn;
    float v = colsumsq[c] * invn - m * m;
    float sc = gamma[c] * rsqrtf(v + BN_EPS);
    scale[c] = sc;
    shift[c] = beta[c] - m * sc;
}

// h += relu(y*scale + shift);  y already includes dinv.
__global__ void bn_apply(const float* __restrict__ acc,
                         const float* __restrict__ scale, const float* __restrict__ shift,
                         float* __restrict__ h) {
    int idx = blockIdx.x * blockDim.x + threadIdx.x;
    int r = idx >> 5;
    int q = idx & 31;
    if (r >= NN) return;
    float4 a = *(const float4*)(acc + (size_t)r * HD + q * 4);
    float4 sc = *(const float4*)(scale + q * 4);
    float4 sf = *(const float4*)(shift + q * 4);
    float4* hp = (float4*)(h + (size_t)r * HD + q * 4);
    float4 hv = *hp;
    hv.x += fmaxf(fmaf(a.x, sc.x, sf.x), 0.f);
    hv.y += fmaxf(fmaf(a.y, sc.y, sf.y), 0.f);
    hv.z += fmaxf(fmaf(a.z, sc.z, sf.z), 0.f);
    hv.w += fmaxf(fmaf(a.w, sc.w, sf.w), 0.f);
    *hp = hv;
}

// gstart[g] = first node index with batch >= g (batch is sorted ascending).
__global__ void group_bounds(const int* __restrict__ batch, int* __restrict__ gstart) {
    int g = blockIdx.x * blockDim.x + threadIdx.x;
    if (g > NG) return;
    if (g == NG) { gstart[NG] = NN; return; }
    int lo = 0, hi = NN;
    while (lo < hi) {
        int mid = (lo + hi) >> 1;
        if (batch[mid] < g) lo = mid + 1; else hi = mid;
    }
    gstart[g] = lo;
}

// pool[g][c] = mean over rows [gstart[g], gstart[g+1]) of h — plain stores, no atomics.
__launch_bounds__(128)
__global__ void pool_mean(const float* __restrict__ h, const int* __restrict__ gstart,
                          float* __restrict__ pool) {
    int g = blockIdx.x;
    int c = threadIdx.x;
    int s = gstart[g], e = gstart[g + 1];
    float acc = 0.f;
    for (int r = s; r < e; ++r) acc += h[(size_t)r * HD + c];
    float ic = 1.0f / fmaxf((float)(e - s), 1.0f);
    pool[(size_t)g * HD + c] = acc * ic;
}

__launch_bounds__(128)
__global__ void out_gemm(const float* __restrict__ pool,
                         const float* __restrict__ Wout, const float* __restrict__ bout,
                         float* __restrict__ out) {
    __shared__ float hb[HD];
    int g = blockIdx.x;
    int c = threadIdx.x;
    hb[c] = pool[(size_t)g * HD + c];
    __syncthreads();
    float o = bout[c];
#pragma unroll 8
    for (int k = 0; k < HD; ++k) o = fmaf(hb[k], Wout[k * HD + c], o);
    out[(size_t)g * HD + c] = o;
}

extern "C" void kernel_launch(void* const* d_in, const int* in_sizes, int n_in,
                              void* d_out, int out_size, void* d_ws, size_t ws_size,
                              hipStream_t stream) {
    const float* x      = (const float*)d_in[0];
    const float* W_in   = (const float*)d_in[1];
    const float* b_in   = (const float*)d_in[2];
    const float* W_conv = (const float*)d_in[3];
    // d_in[4] = b_conv — cancels exactly inside BatchNorm (mean shift only), unused.
    const float* gamma  = (const float*)d_in[5];
    const float* beta   = (const float*)d_in[6];
    const float* W_out  = (const float*)d_in[7];
    const float* b_out  = (const float*)d_in[8];
    const int*   edge   = (const int*)d_in[9];
    const int*   batch  = (const int*)d_in[10];
    float* out = (float*)d_out;

    char* ws = (char*)d_ws;
    float* dinv   = (float*)(ws + OFF_DINV);
    float* h      = (float*)(ws + OFF_H);
    float* u      = (float*)(ws + OFF_U);
    float* acc    = (float*)(ws + OFF_ACC);
    float* pool   = (float*)(ws + OFF_POOL);
    int*   gstart = (int*)(ws + OFF_GSTART);
    float* csum   = (float*)(ws + OFF_CSUM);
    float* csq    = (float*)(ws + OFF_CSQ);
    float* scale  = (float*)(ws + OFF_SCALE);
    float* shift  = (float*)(ws + OFF_SHIFT);
    int*   cnti   = (int*)(ws + OFF_CNTI);
    int*   offs   = (int*)(ws + OFF_OFFS);
    int*   cur    = (int*)(ws + OFF_CUR);
    int*   srcs   = (int*)(ws + OFF_SRCS);
    int*   bsum   = (int*)(ws + OFF_BSUM);

    const int* row = edge;        // sources
    const int* col = edge + NE;   // targets

    // zero: BN stats region, and cnti/cur region
    hipMemsetAsync(ws + OFF_CSUM, 0, OFF_SHIFT + 512 - OFF_CSUM, stream);
    hipMemsetAsync(ws + OFF_CNTI, 0, OFF_SRCS - OFF_CNTI, stream);

    // CSR build + dinv + group bounds
    count_deg_i<<<(NE + 255) / 256, 256, 0, stream>>>(col, cnti);
    finalize_dinv<<<(NN + 255) / 256, 256, 0, stream>>>(cnti, dinv);
    scan_phase1<<<SCAN_B, 256, 0, stream>>>(cnti, bsum);
    scan_phase2<<<1, 64, 0, stream>>>(bsum, offs);
    scan_phase3<<<SCAN_B, 256, 0, stream>>>(cnti, bsum, offs);
    fill_csr<<<(NE + 255) / 256, 256, 0, stream>>>(row, col, offs, cur, srcs);
    group_bounds<<<(NG + 256) / 256, 256, 0, stream>>>(batch, gstart);

    // h = x @ W_in + b_in
    gemm128<true, false><<<(NN + 127) / 128, 512, 0, stream>>>(
        x, W_in, b_in, nullptr, h, NN);

    for (int l = 0; l < NL; ++l) {
        // u = (h @ W_conv[l]) * dinv
        gemm128<false, true><<<(NN + 127) / 128, 512, 0, stream>>>(
            h, W_conv + (size_t)l * HD * HD, nullptr, dinv, u, NN);
        gather_bn<<<GATHER_BLOCKS, 256, 0, stream>>>(
            offs, srcs, u, dinv, acc, csum + l * HD, csq + l * HD);
        bn_finalize<<<1, HD, 0, stream>>>(
            csum + l * HD, csq + l * HD, gamma + l * HD, beta + l * HD, scale, shift);
        bn_apply<<<((size_t)NN * 32 + 255) / 256, 256, 0, stream>>>(
            acc, scale, shift, h);
    }

    pool_mean<<<NG, 128, 0, stream>>>(h, gstart, pool);
    out_gemm<<<NG, 128, 0, stream>>>(pool, W_out, b_out, out);
}